// Round 2
// baseline (762.804 us; speedup 1.0000x reference)
//
#include <hip/hip_runtime.h>
#include <hip/hip_bf16.h>

// LSTMCell fused: ifgo = [x0 h0 x1 h1] @ W  (M=1024, N=8192, K=4096) + gates.
// bf16 MFMA 16x16x32, 128x128 tile, BK=64, 256 thr (4 waves 2x2), 512 blocks.
// Round 2: coalesced B loads (float4 rows of W) + in-register transpose to
// k-contiguous bf16x8 + XOR-swizzled Bs (kills the 16-way write conflicts of
// round 1), pk bf16 conversion, and register prefetch of iter k+1 issued after
// the barrier so global latency hides under the MFMA phase.

typedef short bf16x8 __attribute__((ext_vector_type(8)));   // 8 bf16 (4 VGPRs)
typedef float f32x4  __attribute__((ext_vector_type(4)));

#define LDKA 72   // A LDS stride in shorts (64 + 8): A write/read pattern ~2-way

__device__ __forceinline__ unsigned pkcvt(float a, float b) {
#if defined(__has_builtin) && __has_builtin(__builtin_amdgcn_cvt_pk_bf16_f32)
  typedef __bf16 bf16x2_t __attribute__((ext_vector_type(2)));
  bf16x2_t r = __builtin_amdgcn_cvt_pk_bf16_f32(a, b);
  union { bf16x2_t v; unsigned u; } cv; cv.v = r;
  return cv.u;
#else
  unsigned ua = __float_as_uint(a), ub = __float_as_uint(b);
  ua = (ua + 0x7fffu + ((ua >> 16) & 1u)) >> 16;
  ub = (ub + 0x7fffu + ((ub >> 16) & 1u)) & 0xffff0000u;
  return ua | ub;
#endif
}

union pk8 { unsigned u[4]; bf16x8 v; };

__global__ __launch_bounds__(256, 2)
void lstm_fused(const float* __restrict__ x, const float* __restrict__ h,
                const float* __restrict__ cin, const float* __restrict__ W,
                float* __restrict__ out)
{
  __shared__ short As[128 * LDKA];   // A[m][k], k-contiguous, padded (18 KB)
  __shared__ short Bs[128 * 64];     // B^T[c][k], 8-chunk XOR swizzle (16 KB)

  const int tid  = threadIdx.x;
  const int lane = tid & 63;
  const int wid  = tid >> 6;
  const int wr   = wid >> 1;
  const int wc   = wid & 1;

  const int bid     = blockIdx.x;
  const int rowblk  = bid >> 6;          // 0..7   (bid%8==colblk%8 -> XCD share)
  const int colblk  = bid & 63;          // 0..63
  const int n       = colblk >> 5;       // n-split
  const int u0      = (colblk & 31) * 32;
  const int rowbase = rowblk * 128;

  // A staging: thread owns rows {ar, ar+64}, k-cols [ac, ac+16)
  const int ar = tid >> 2;
  const int ac = (tid & 3) * 16;
  // B staging: thread owns k-chunk bk (8 k-rows), 4 consecutive W cols
  const int bk    = tid >> 5;            // 0..7
  const int bl    = tid & 31;
  const int bgate = bl >> 3;             // 0..3
  const int buq   = bl & 7;              // u-quad 0..7
  const int gcolb = bgate * 1024 + u0 + 4 * buq;   // W col base (+i)

  const int am   = lane & 15;
  const int quad = lane >> 4;

  f32x4 acc[4][4];
  const f32x4 zero = {0.f, 0.f, 0.f, 0.f};
  #pragma unroll
  for (int i = 0; i < 4; ++i)
    #pragma unroll
    for (int j = 0; j < 4; ++j) acc[i][j] = zero;

  float4 areg[2][4];   // 2 rows x 16 k
  float4 breg[8];      // 8 k-rows x 4 cols

  auto load_tiles = [&](int kt) {
    const int blk = kt >> 4;
    const float* asrc = (blk & 1) ? h : x;
    const int cb = (blk >> 1) * 1024 + (kt & 15) * 64;
    #pragma unroll
    for (int rr = 0; rr < 2; ++rr) {
      const float4* p = (const float4*)(asrc + (rowbase + ar + rr * 64) * 2048 + cb + ac);
      #pragma unroll
      for (int q = 0; q < 4; ++q) areg[rr][q] = p[q];
    }
    const int kq = kt >> 5;
    const int d0 = (kt & 31) * 64;
    const float* wp = W + ((kq * 2 + n) * 2048 + d0 + bk * 8) * 4096 + gcolb;
    #pragma unroll
    for (int j = 0; j < 8; ++j) breg[j] = *(const float4*)(wp + j * 4096);
  };

  load_tiles(0);

  for (int kt = 0; kt < 64; ++kt) {
    // ---- convert to bf16 (frees areg/breg before the prefetch) ----
    bf16x8 aw[2][2];
    #pragma unroll
    for (int rr = 0; rr < 2; ++rr) {
      pk8 p0, p1;
      #pragma unroll
      for (int q = 0; q < 2; ++q) {
        p0.u[q * 2 + 0] = pkcvt(areg[rr][q].x, areg[rr][q].y);
        p0.u[q * 2 + 1] = pkcvt(areg[rr][q].z, areg[rr][q].w);
        p1.u[q * 2 + 0] = pkcvt(areg[rr][q + 2].x, areg[rr][q + 2].y);
        p1.u[q * 2 + 1] = pkcvt(areg[rr][q + 2].z, areg[rr][q + 2].w);
      }
      aw[rr][0] = p0.v; aw[rr][1] = p1.v;
    }
    bf16x8 bw[4];   // bw[i] = column gcolb+i, 8 k-values packed
    {
      pk8 pc[4];
      #pragma unroll
      for (int j = 0; j < 4; ++j) {
        pc[0].u[j] = pkcvt(breg[2 * j].x, breg[2 * j + 1].x);
        pc[1].u[j] = pkcvt(breg[2 * j].y, breg[2 * j + 1].y);
        pc[2].u[j] = pkcvt(breg[2 * j].z, breg[2 * j + 1].z);
        pc[3].u[j] = pkcvt(breg[2 * j].w, breg[2 * j + 1].w);
      }
      #pragma unroll
      for (int i = 0; i < 4; ++i) bw[i] = pc[i].v;
    }

    __syncthreads();   // previous iter's ds_reads complete before overwrite
    #pragma unroll
    for (int rr = 0; rr < 2; ++rr) {
      *(bf16x8*)&As[(ar + rr * 64) * LDKA + ac]     = aw[rr][0];
      *(bf16x8*)&As[(ar + rr * 64) * LDKA + ac + 8] = aw[rr][1];
    }
    // B: column c = 16*buq + 4*i + bgate, chunk bk XOR-swizzled by (c&7).
    // Lane-rotated order (i+buq)&3 spreads c&7 across lanes -> ~2-way max.
    #pragma unroll
    for (int ii = 0; ii < 4; ++ii) {
      const int i = (ii + buq) & 3;
      const int c = 16 * buq + 4 * i + bgate;
      *(bf16x8*)&Bs[c * 64 + ((bk ^ (c & 7)) * 8)] = bw[i];
    }
    __syncthreads();

    // ---- prefetch next tile: VMEM flies under the MFMA phase ----
    if (kt < 63) load_tiles(kt + 1);

    // ---- MFMA: 2 k-steps of 32 ----
    #pragma unroll
    for (int s = 0; s < 2; ++s) {
      bf16x8 af[4], bfr[4];
      #pragma unroll
      for (int tm = 0; tm < 4; ++tm)
        af[tm] = *(const bf16x8*)&As[(wr * 64 + tm * 16 + am) * LDKA + s * 32 + quad * 8];
      #pragma unroll
      for (int tn = 0; tn < 4; ++tn) {
        const int c = wc * 64 + tn * 16 + am;
        bfr[tn] = *(const bf16x8*)&Bs[c * 64 + (((s * 4 + quad) ^ (am & 7)) * 8)];
      }
      #pragma unroll
      for (int tm = 0; tm < 4; ++tm)
        #pragma unroll
        for (int tn = 0; tn < 4; ++tn)
          acc[tm][tn] = __builtin_amdgcn_mfma_f32_16x16x32_bf16(
              af[tm], bfr[tn], acc[tm][tn], 0, 0, 0);
    }
  }

  // ---- fused LSTM epilogue ----
  // C/D: col = lane&15 (c_il), row = quad*4 + reg. c_il = 4*u + gate ->
  // lanes {base..base+3} hold i,f,g,o of one (row, u).
  const int BU   = 1024 * 2048;
  const int g    = lane & 3;
  const int base = lane & ~3;
  #pragma unroll
  for (int tn = 0; tn < 4; ++tn) {
    const int cil_ep = wc * 64 + tn * 16 + am;
    const int u   = u0 + (cil_ep >> 2);
    const int col = n * 1024 + u;
    #pragma unroll
    for (int tm = 0; tm < 4; ++tm) {
      const int brow0 = rowbase + wr * 64 + tm * 16 + quad * 4;
      #pragma unroll
      for (int r = 0; r < 4; ++r) {
        const int brow = brow0 + r;
        const float val = acc[tm][tn][r];
        const float xs  = (g == 2) ? 2.f * val : val;
        const float sg  = 1.f / (1.f + __expf(-xs));
        const float act = (g == 2) ? (2.f * sg - 1.f) : sg;
        const float ig = __shfl(act, base + 0, 64);
        const float fg = __shfl(act, base + 1, 64);
        const float gg = __shfl(act, base + 2, 64);
        const float og = __shfl(act, base + 3, 64);
        const float cold = cin[brow * 2048 + col];
        const float nc = fg * cold + ig * gg;
        const float th = 1.f - 2.f / (1.f + __expf(2.f * nc));
        const float nh = og * th;
        if (g == 0) out[brow * 2048 + col]      = nh;   // new_h
        if (g == 1) out[BU + brow * 2048 + col] = nc;   // new_c
      }
    }
  }
}

extern "C" void kernel_launch(void* const* d_in, const int* in_sizes, int n_in,
                              void* d_out, int out_size, void* d_ws, size_t ws_size,
                              hipStream_t stream) {
  const float* x = (const float*)d_in[0];
  const float* h = (const float*)d_in[1];
  const float* c = (const float*)d_in[2];
  const float* W = (const float*)d_in[3];
  float* out = (float*)d_out;
  lstm_fused<<<dim3(512), dim3(256), 0, stream>>>(x, h, c, W, out);
}

// Round 3
// 583.517 us; speedup vs baseline: 1.3073x; 1.3073x over previous
//
#include <hip/hip_runtime.h>
#include <hip/hip_bf16.h>

// LSTMCell fused: ifgo = [x0 h0 x1 h1] @ W  (M=1024, N=8192, K=4096) + gates.
// Round 3: 128x64 tile (grid 1024 -> 4 blocks/CU, 16 waves/CU), BK=64,
// unpadded 64-short LDS rows with chunk-XOR swizzle (bank-minimal on all four
// LDS paths, statically unrolled — round 2's dynamic register indexing removed),
// register prefetch of iter kt+1 issued after barrier 2 so VMEM hides under MFMA.

typedef short bf16x8 __attribute__((ext_vector_type(8)));   // 8 bf16 (4 VGPRs)
typedef float f32x4  __attribute__((ext_vector_type(4)));

__device__ __forceinline__ unsigned pkcvt(float a, float b) {
#if defined(__has_builtin) && __has_builtin(__builtin_amdgcn_cvt_pk_bf16_f32)
  typedef __bf16 bf16x2_t __attribute__((ext_vector_type(2)));
  bf16x2_t r = __builtin_amdgcn_cvt_pk_bf16_f32(a, b);
  union { bf16x2_t v; unsigned u; } cv; cv.v = r;
  return cv.u;
#else
  unsigned ua = __float_as_uint(a), ub = __float_as_uint(b);
  ua = (ua + 0x7fffu + ((ua >> 16) & 1u)) >> 16;
  ub = (ub + 0x7fffu + ((ub >> 16) & 1u)) & 0xffff0000u;
  return ua | ub;
#endif
}

union pk8 { unsigned u[4]; bf16x8 v; };

__global__ __launch_bounds__(256, 4)
void lstm_fused(const float* __restrict__ x, const float* __restrict__ h,
                const float* __restrict__ cin, const float* __restrict__ W,
                float* __restrict__ out)
{
  // Row r lives at As[r*64]; 16B chunk ch stored at physical chunk ch^(r&7).
  __shared__ short As[128 * 64];   // 16 KB: A[m][k]
  __shared__ short Bs[64 * 64];    // 8 KB:  B^T[c][k], c = 4*u + gate

  const int tid  = threadIdx.x;
  const int lane = tid & 63;
  const int wid  = tid >> 6;
  const int wr   = wid >> 1;        // wave row half: rows wr*64 + [0,64)
  const int wc   = wid & 1;         // wave col half: cols wc*32 + [0,32)

  // Grid: 1024 = 8 rowblks x 128 colblks, bid = rowblk*128 + colblk so the 8
  // row-siblings sharing a W strip have equal bid%8 -> same XCD (L2 reuse).
  const int bid     = blockIdx.x;
  const int rowblk  = bid >> 7;
  const int colblk  = bid & 127;
  const int n       = colblk >> 6;           // n-split 0..1
  const int u0      = (colblk & 63) * 16;    // 16 u-values per tile
  const int rowbase = rowblk * 128;

  // A staging: thread owns rows {ar, ar+64}, k-chunks {aq*2, aq*2+1} (16 k)
  const int ar = tid >> 2;
  const int aq = tid & 3;
  // B staging: thread owns tile-col bc (= 4*u_local + gate), k-rows kgrp*16..+15
  const int bc   = tid & 63;
  const int bgt  = bc & 3;
  const int bu   = bc >> 2;
  const int kgrp = tid >> 6;
  const int gcol = bgt * 1024 + u0 + bu;     // col in the 4096-wide W slab

  const int am   = lane & 15;
  const int quad = lane >> 4;

  f32x4 acc[4][2];
  const f32x4 zero = {0.f, 0.f, 0.f, 0.f};
  #pragma unroll
  for (int i = 0; i < 4; ++i)
    #pragma unroll
    for (int j = 0; j < 2; ++j) acc[i][j] = zero;

  float4 areg[2][4];   // 2 rows x 16 k
  float  breg[16];     // 16 k of one W column

  auto load_tiles = [&](int kt) {
    const int blk = kt >> 4;
    const float* asrc = (blk & 1) ? h : x;
    const int cb = (blk >> 1) * 1024 + (kt & 15) * 64;
    #pragma unroll
    for (int rr = 0; rr < 2; ++rr) {
      const float4* p = (const float4*)(asrc + (rowbase + ar + rr * 64) * 2048 + cb + aq * 16);
      #pragma unroll
      for (int q = 0; q < 4; ++q) areg[rr][q] = p[q];
    }
    const int kq = kt >> 5;
    const int wrow0 = (kq * 2 + n) * 2048 + (kt & 31) * 64;
    const float* wp = W + (wrow0 + kgrp * 16) * 4096 + gcol;
    #pragma unroll
    for (int j = 0; j < 16; ++j) breg[j] = wp[j * 4096];   // 64 lanes -> 4 full lines/instr
  };

  load_tiles(0);

  for (int kt = 0; kt < 64; ++kt) {
    // ---- convert to bf16 (statically indexed throughout) ----
    bf16x8 aw[2][2];
    #pragma unroll
    for (int rr = 0; rr < 2; ++rr) {
      pk8 p0, p1;
      p0.u[0] = pkcvt(areg[rr][0].x, areg[rr][0].y);
      p0.u[1] = pkcvt(areg[rr][0].z, areg[rr][0].w);
      p0.u[2] = pkcvt(areg[rr][1].x, areg[rr][1].y);
      p0.u[3] = pkcvt(areg[rr][1].z, areg[rr][1].w);
      p1.u[0] = pkcvt(areg[rr][2].x, areg[rr][2].y);
      p1.u[1] = pkcvt(areg[rr][2].z, areg[rr][2].w);
      p1.u[2] = pkcvt(areg[rr][3].x, areg[rr][3].y);
      p1.u[3] = pkcvt(areg[rr][3].z, areg[rr][3].w);
      aw[rr][0] = p0.v; aw[rr][1] = p1.v;
    }
    bf16x8 bw[2];
    {
      pk8 q0, q1;
      #pragma unroll
      for (int j = 0; j < 4; ++j) {
        q0.u[j] = pkcvt(breg[2 * j],     breg[2 * j + 1]);
        q1.u[j] = pkcvt(breg[8 + 2 * j], breg[8 + 2 * j + 1]);
      }
      bw[0] = q0.v; bw[1] = q1.v;
    }

    __syncthreads();   // previous iter's ds_reads complete before overwrite
    #pragma unroll
    for (int rr = 0; rr < 2; ++rr) {
      const int row = ar + rr * 64;
      #pragma unroll
      for (int hh = 0; hh < 2; ++hh)
        *(bf16x8*)&As[row * 64 + (((aq * 2 + hh) ^ (ar & 7)) * 8)] = aw[rr][hh];
    }
    #pragma unroll
    for (int hh = 0; hh < 2; ++hh)
      *(bf16x8*)&Bs[bc * 64 + (((kgrp * 2 + hh) ^ (bc & 7)) * 8)] = bw[hh];
    __syncthreads();

    // ---- prefetch next tile: VMEM flies under the MFMA phase ----
    if (kt < 63) load_tiles(kt + 1);

    // ---- MFMA: 2 k-steps of 32; swizzled fragment reads ----
    #pragma unroll
    for (int s = 0; s < 2; ++s) {
      const int sw = ((s * 4 + quad) ^ (am & 7)) * 8;
      bf16x8 af[4], bfr[2];
      #pragma unroll
      for (int tm = 0; tm < 4; ++tm)
        af[tm] = *(const bf16x8*)&As[(wr * 64 + tm * 16 + am) * 64 + sw];
      #pragma unroll
      for (int tn = 0; tn < 2; ++tn)
        bfr[tn] = *(const bf16x8*)&Bs[(wc * 32 + tn * 16 + am) * 64 + sw];
      #pragma unroll
      for (int tm = 0; tm < 4; ++tm)
        #pragma unroll
        for (int tn = 0; tn < 2; ++tn)
          acc[tm][tn] = __builtin_amdgcn_mfma_f32_16x16x32_bf16(
              af[tm], bfr[tn], acc[tm][tn], 0, 0, 0);
    }
  }

  // ---- fused LSTM epilogue ----
  // C/D: col = lane&15 (tile col c_il = 4*u + gate), row = quad*4 + reg.
  // Lanes base..base+3 hold i,f,g,o of one (row, u): combine with 4 shfls.
  const int BU   = 1024 * 2048;
  const int g    = lane & 3;
  const int base = lane & ~3;
  #pragma unroll
  for (int tn = 0; tn < 2; ++tn) {
    const int cil = wc * 32 + tn * 16 + am;
    const int col = n * 1024 + u0 + (cil >> 2);
    #pragma unroll
    for (int tm = 0; tm < 4; ++tm) {
      const int brow0 = rowbase + wr * 64 + tm * 16 + quad * 4;
      #pragma unroll
      for (int r = 0; r < 4; ++r) {
        const int brow = brow0 + r;
        const float val = acc[tm][tn][r];
        const float xs  = (g == 2) ? 2.f * val : val;       // tanh via sigmoid
        const float sg  = 1.f / (1.f + __expf(-xs));
        const float act = (g == 2) ? (2.f * sg - 1.f) : sg;
        const float ig = __shfl(act, base + 0, 64);
        const float fg = __shfl(act, base + 1, 64);
        const float gg = __shfl(act, base + 2, 64);
        const float og = __shfl(act, base + 3, 64);
        const float cold = cin[brow * 2048 + col];
        const float nc = fg * cold + ig * gg;
        const float th = 1.f - 2.f / (1.f + __expf(2.f * nc));
        const float nh = og * th;
        if (g == 0) out[brow * 2048 + col]      = nh;   // new_h
        if (g == 1) out[BU + brow * 2048 + col] = nc;   // new_c
      }
    }
  }
}

extern "C" void kernel_launch(void* const* d_in, const int* in_sizes, int n_in,
                              void* d_out, int out_size, void* d_ws, size_t ws_size,
                              hipStream_t stream) {
  const float* x = (const float*)d_in[0];
  const float* h = (const float*)d_in[1];
  const float* c = (const float*)d_in[2];
  const float* W = (const float*)d_in[3];
  float* out = (float*)d_out;
  lstm_fused<<<dim3(1024), dim3(256), 0, stream>>>(x, h, c, W, out);
}

// Round 4
// 453.436 us; speedup vs baseline: 1.6823x; 1.2869x over previous
//
#include <hip/hip_runtime.h>
#include <hip/hip_bf16.h>

// LSTMCell fused: ifgo = [x0 h0 x1 h1] @ W  (M=1024, N=8192, K=4096) + gates.
// Round 4: 128x128 tile (grid 512 -> low W re-fetch, round-1 HBM profile) with
// 512-thread blocks (8 waves 2x4 -> 16 waves/CU at 2 blocks/CU) for latency
// hiding. Round-3's verified zero-conflict chunk-XOR LDS swizzle; register
// prefetch of iter kt+1 after barrier 2. Gate-interleaved B cols -> epilogue
// combines i,f,g,o with 4 intra-quad shfls, no second kernel, no workspace.

typedef short bf16x8 __attribute__((ext_vector_type(8)));   // 8 bf16 (4 VGPRs)
typedef float f32x4  __attribute__((ext_vector_type(4)));

__device__ __forceinline__ unsigned pkcvt(float a, float b) {
#if defined(__has_builtin) && __has_builtin(__builtin_amdgcn_cvt_pk_bf16_f32)
  typedef __bf16 bf16x2_t __attribute__((ext_vector_type(2)));
  bf16x2_t r = __builtin_amdgcn_cvt_pk_bf16_f32(a, b);
  union { bf16x2_t v; unsigned u; } cv; cv.v = r;
  return cv.u;
#else
  unsigned ua = __float_as_uint(a), ub = __float_as_uint(b);
  ua = (ua + 0x7fffu + ((ua >> 16) & 1u)) >> 16;
  ub = (ub + 0x7fffu + ((ub >> 16) & 1u)) & 0xffff0000u;
  return ua | ub;
#endif
}

union pk8 { unsigned u[4]; bf16x8 v; };

__global__ __launch_bounds__(512, 4)
void lstm_fused(const float* __restrict__ x, const float* __restrict__ h,
                const float* __restrict__ cin, const float* __restrict__ W,
                float* __restrict__ out)
{
  // Row r at base r*64 shorts; 16B chunk ch stored at physical chunk ch^(r&7).
  __shared__ short As[128 * 64];   // 16 KB: A[m][k]
  __shared__ short Bs[128 * 64];   // 16 KB: B^T[c][k], c = 4*u_local + gate

  const int tid  = threadIdx.x;
  const int lane = tid & 63;
  const int wid  = tid >> 6;
  const int wr   = wid >> 2;        // wave row half: rows wr*64 + [0,64)
  const int wq   = wid & 3;         // wave col quarter: cols wq*32 + [0,32)

  // Grid: 512 = 8 rowblks x 64 colblks; bid%8 == colblk%8 -> the 8 row-siblings
  // sharing a W strip land on one XCD (L2 reuse of W).
  const int bid     = blockIdx.x;
  const int rowblk  = bid >> 6;
  const int colblk  = bid & 63;
  const int n       = colblk >> 5;           // n-split 0..1
  const int u0      = (colblk & 31) * 32;    // 32 u-values per tile
  const int rowbase = rowblk * 128;

  // A staging: thread owns row ar, k-chunks {2aq, 2aq+1} (16 k)
  const int ar = tid >> 2;
  const int aq = tid & 3;
  // B staging: thread owns tile-col bc (= 4*u_local + gate), k-rows kgrp*16..+15
  const int bc   = tid & 127;
  const int bgt  = bc & 3;
  const int bu   = bc >> 2;
  const int kgrp = tid >> 7;                 // 0..3
  const int gcol = bgt * 1024 + u0 + bu;     // col in the 4096-wide W slab

  const int am   = lane & 15;
  const int quad = lane >> 4;

  f32x4 acc[4][2];
  const f32x4 zero = {0.f, 0.f, 0.f, 0.f};
  #pragma unroll
  for (int i = 0; i < 4; ++i)
    #pragma unroll
    for (int j = 0; j < 2; ++j) acc[i][j] = zero;

  float4 areg[4];   // 1 row x 16 k
  float  breg[16];  // 16 k of one W column

  auto load_tiles = [&](int kt) {
    const int blk = kt >> 4;
    const float* asrc = (blk & 1) ? h : x;
    const int cb = (blk >> 1) * 1024 + (kt & 15) * 64;
    const float4* p = (const float4*)(asrc + (rowbase + ar) * 2048 + cb + aq * 16);
    #pragma unroll
    for (int q = 0; q < 4; ++q) areg[q] = p[q];
    const int kq = kt >> 5;
    const float* wp = W + ((kq * 2 + n) * 2048 + (kt & 31) * 64 + kgrp * 16) * 4096 + gcol;
    #pragma unroll
    for (int j = 0; j < 16; ++j) breg[j] = wp[j * 4096];   // 64 lanes -> 4 full lines/instr
  };

  load_tiles(0);

  for (int kt = 0; kt < 64; ++kt) {
    // ---- convert to bf16 (statically indexed) ----
    bf16x8 aw[2];
    {
      pk8 p0, p1;
      p0.u[0] = pkcvt(areg[0].x, areg[0].y);
      p0.u[1] = pkcvt(areg[0].z, areg[0].w);
      p0.u[2] = pkcvt(areg[1].x, areg[1].y);
      p0.u[3] = pkcvt(areg[1].z, areg[1].w);
      p1.u[0] = pkcvt(areg[2].x, areg[2].y);
      p1.u[1] = pkcvt(areg[2].z, areg[2].w);
      p1.u[2] = pkcvt(areg[3].x, areg[3].y);
      p1.u[3] = pkcvt(areg[3].z, areg[3].w);
      aw[0] = p0.v; aw[1] = p1.v;
    }
    bf16x8 bw[2];
    {
      pk8 q0, q1;
      #pragma unroll
      for (int j = 0; j < 4; ++j) {
        q0.u[j] = pkcvt(breg[2 * j],     breg[2 * j + 1]);
        q1.u[j] = pkcvt(breg[8 + 2 * j], breg[8 + 2 * j + 1]);
      }
      bw[0] = q0.v; bw[1] = q1.v;
    }

    __syncthreads();   // previous iter's ds_reads complete before overwrite
    #pragma unroll
    for (int hh = 0; hh < 2; ++hh)
      *(bf16x8*)&As[ar * 64 + (((aq * 2 + hh) ^ (ar & 7)) * 8)] = aw[hh];
    #pragma unroll
    for (int hh = 0; hh < 2; ++hh)
      *(bf16x8*)&Bs[bc * 64 + (((kgrp * 2 + hh) ^ (bc & 7)) * 8)] = bw[hh];
    __syncthreads();

    // ---- prefetch next tile: VMEM flies under the MFMA phase ----
    if (kt < 63) load_tiles(kt + 1);

    // ---- MFMA: 2 k-steps of 32; swizzled fragment reads ----
    #pragma unroll
    for (int s = 0; s < 2; ++s) {
      const int sw = ((s * 4 + quad) ^ (am & 7)) * 8;
      bf16x8 af[4], bfr[2];
      #pragma unroll
      for (int tm = 0; tm < 4; ++tm)
        af[tm] = *(const bf16x8*)&As[(wr * 64 + tm * 16 + am) * 64 + sw];
      #pragma unroll
      for (int tn = 0; tn < 2; ++tn)
        bfr[tn] = *(const bf16x8*)&Bs[(wq * 32 + tn * 16 + am) * 64 + sw];
      #pragma unroll
      for (int tm = 0; tm < 4; ++tm)
        #pragma unroll
        for (int tn = 0; tn < 2; ++tn)
          acc[tm][tn] = __builtin_amdgcn_mfma_f32_16x16x32_bf16(
              af[tm], bfr[tn], acc[tm][tn], 0, 0, 0);
    }
  }

  // ---- fused LSTM epilogue ----
  // C/D: col = lane&15 (tile col c_il = 4*u + gate), row = quad*4 + reg.
  // Lanes base..base+3 hold i,f,g,o of one (row, u): combine with 4 shfls.
  const int BU   = 1024 * 2048;
  const int g    = lane & 3;
  const int base = lane & ~3;
  #pragma unroll
  for (int tn = 0; tn < 2; ++tn) {
    const int cil = wq * 32 + tn * 16 + am;
    const int col = n * 1024 + u0 + (cil >> 2);
    #pragma unroll
    for (int tm = 0; tm < 4; ++tm) {
      const int brow0 = rowbase + wr * 64 + tm * 16 + quad * 4;
      #pragma unroll
      for (int r = 0; r < 4; ++r) {
        const int brow = brow0 + r;
        const float val = acc[tm][tn][r];
        const float xs  = (g == 2) ? 2.f * val : val;       // tanh via sigmoid
        const float sg  = 1.f / (1.f + __expf(-xs));
        const float act = (g == 2) ? (2.f * sg - 1.f) : sg;
        const float ig = __shfl(act, base + 0, 64);
        const float fg = __shfl(act, base + 1, 64);
        const float gg = __shfl(act, base + 2, 64);
        const float og = __shfl(act, base + 3, 64);
        const float cold = cin[brow * 2048 + col];
        const float nc = fg * cold + ig * gg;
        const float th = 1.f - 2.f / (1.f + __expf(2.f * nc));
        const float nh = og * th;
        if (g == 0) out[brow * 2048 + col]      = nh;   // new_h
        if (g == 1) out[BU + brow * 2048 + col] = nc;   // new_c
      }
    }
  }
}

extern "C" void kernel_launch(void* const* d_in, const int* in_sizes, int n_in,
                              void* d_out, int out_size, void* d_ws, size_t ws_size,
                              hipStream_t stream) {
  const float* x = (const float*)d_in[0];
  const float* h = (const float*)d_in[1];
  const float* c = (const float*)d_in[2];
  const float* W = (const float*)d_in[3];
  float* out = (float*)d_out;
  lstm_fused<<<dim3(512), dim3(512), 0, stream>>>(x, h, c, W, out);
}

// Round 5
// 323.364 us; speedup vs baseline: 2.3590x; 1.4022x over previous
//
#include <hip/hip_runtime.h>
#include <hip/hip_bf16.h>

// LSTMCell fused: ifgo = [x0 h0 x1 h1] @ W  (M=1024, N=8192, K=4096) + gates.
// Round 5: two-phase. Prep kernels convert W (fp32->bf16, [k][col] -> [c][k]
// gate-interleaved transpose) and xh into d_ws, PRE-SWIZZLED so the main
// kernel's linear global_load_lds produces the round-3-verified zero-conflict
// chunk-XOR LDS layout. Main kernel is the m97 structure: 128x128 tile, BK=64,
// 256 thr (2x2 waves, 4x4 acc each), global_load_lds width=16, 2 barriers,
// ds_read_b128 frags, 32 MFMA/iter, fused LSTM epilogue.
// Host falls back to the round-4 single kernel if ws_size < 76 MB.

typedef short bf16x8 __attribute__((ext_vector_type(8)));   // 8 bf16 (4 VGPRs)
typedef float f32x4  __attribute__((ext_vector_type(4)));

__device__ __forceinline__ unsigned pkcvt(float a, float b) {
#if defined(__has_builtin) && __has_builtin(__builtin_amdgcn_cvt_pk_bf16_f32)
  typedef __bf16 bf16x2_t __attribute__((ext_vector_type(2)));
  bf16x2_t r = __builtin_amdgcn_cvt_pk_bf16_f32(a, b);
  union { bf16x2_t v; unsigned u; } cv; cv.v = r;
  return cv.u;
#else
  unsigned ua = __float_as_uint(a), ub = __float_as_uint(b);
  ua = (ua + 0x7fffu + ((ua >> 16) & 1u)) >> 16;
  ub = (ub + 0x7fffu + ((ub >> 16) & 1u)) & 0xffff0000u;
  return ua | ub;
#endif
}

union pk8 { unsigned u[4]; bf16x8 v; };

__device__ __forceinline__ void gl_lds16(const void* g, void* l) {
  __builtin_amdgcn_global_load_lds(
      (const __attribute__((address_space(1))) unsigned*)g,
      (__attribute__((address_space(3))) unsigned*)l, 16, 0, 0);
}

// ---------- prep A: xh -> bf16 wsA[row][k], chunk ch pre-XORed by row&7 ----------
__global__ __launch_bounds__(256)
void prep_xh(const float* __restrict__ x, const float* __restrict__ h, void* wsAv)
{
  const int gid = blockIdx.x * 256 + threadIdx.x;   // 524288 total
  const int row = gid >> 9;
  const int r9  = gid & 511;
  const int kt  = r9 >> 3;
  const int pc  = r9 & 7;
  const int lc  = pc ^ (row & 7);
  const int k0  = kt * 64 + lc * 8;
  const int blk = k0 >> 10;                          // 0..3 -> x0,h0,x1,h1
  const float* src = ((blk & 1) ? h : x) + row * 2048 + (blk >> 1) * 1024 + (k0 & 1023);
  const float4 p0 = ((const float4*)src)[0];
  const float4 p1 = ((const float4*)src)[1];
  pk8 o;
  o.u[0] = pkcvt(p0.x, p0.y); o.u[1] = pkcvt(p0.z, p0.w);
  o.u[2] = pkcvt(p1.x, p1.y); o.u[3] = pkcvt(p1.z, p1.w);
  *(bf16x8*)((char*)wsAv + (size_t)row * 8192 + kt * 128 + pc * 16) = o.v;
}

// ---------- prep B: W[k][col] -> bf16 wsB[n][c][k], c = 4*u + gate, pre-swizzled ----------
__global__ __launch_bounds__(256)
void prep_w(const float* __restrict__ W, void* wsBv)
{
  __shared__ short Ls[64 * 72];                      // 64 c x 64 k, padded
  const int t  = threadIdx.x;
  const int pb = blockIdx.x;                         // 8192 = 2n x 64c x 64k tiles
  const int kT = pb & 63;
  const int cT = (pb >> 6) & 63;
  const int n  = pb >> 12;
  const int c0 = cT * 64;
  const int k0 = kT * 64;
  const int kq = k0 >> 11;
  const int krow0 = k0 & 2047;

  // phase 1: coalesced read (lanes vary c), 16 strided k per thread
  const int c_l  = t & 63;
  const int kgrp = t >> 6;
  const int c    = c0 + c_l;
  const int col  = (c & 3) * 1024 + (c >> 2);        // gate*1024 + u
  const float* src = W + ((size_t)(kq * 2 + n) * 2048 + krow0 + kgrp * 16) * 4096 + col;
  #pragma unroll
  for (int i = 0; i < 16; i += 2) {
    const float a = src[(size_t)i * 4096];
    const float b = src[(size_t)(i + 1) * 4096];
    *(unsigned*)&Ls[c_l * 72 + kgrp * 16 + i] = pkcvt(a, b);
  }
  __syncthreads();
  // phase 2: write k-major 16B chunks, pre-swizzled by c&7, coalesced in pc
  #pragma unroll
  for (int half = 0; half < 2; ++half) {
    const int j   = t + half * 256;                  // 512 chunks per tile
    const int cl2 = j >> 3;
    const int pc  = j & 7;
    const int cc  = c0 + cl2;
    const int lc2 = pc ^ (cc & 7);
    const bf16x8 v = *(const bf16x8*)&Ls[cl2 * 72 + lc2 * 8];
    *(bf16x8*)((char*)wsBv + ((size_t)(n * 4096 + cc) * 8192) + (size_t)(k0 + pc * 8) * 2) = v;
  }
}

// ---------- main: m97-structure GEMM + fused LSTM epilogue ----------
__global__ __launch_bounds__(256, 3)
void lstm_mm(const void* wsAv, const void* wsBv,
             const float* __restrict__ cin, float* __restrict__ out)
{
  __shared__ short As[128 * 64];   // 16 KB, pre-swizzled layout arrives via linear copy
  __shared__ short Bs[128 * 64];   // 16 KB

  const int tid  = threadIdx.x;
  const int lane = tid & 63;
  const int wid  = tid >> 6;
  const int wr   = wid >> 1;
  const int wc   = wid & 1;

  const int bid     = blockIdx.x;                 // 512 = 8 rowblk x 64 colblk
  const int rowblk  = bid >> 6;                   // bid%8==colblk%8 -> XCD share
  const int colblk  = bid & 63;
  const int n       = colblk >> 5;
  const int u0      = (colblk & 31) * 32;
  const int rowbase = rowblk * 128;

  const int am   = lane & 15;
  const int quad = lane >> 4;
  const int rA   = lane >> 3;                     // row within 8-row group
  const int pcA  = lane & 7;

  const char* wsA = (const char*)wsAv;
  const char* wsB = (const char*)wsBv;
  const size_t aRowBase = (size_t)(rowbase + wid * 32) * 8192;
  const size_t bRowBase = (size_t)(n * 4096 + 4 * u0 + wid * 32) * 8192;

  f32x4 acc[4][4];
  const f32x4 zero = {0.f, 0.f, 0.f, 0.f};
  #pragma unroll
  for (int i = 0; i < 4; ++i)
    #pragma unroll
    for (int j = 0; j < 4; ++j) acc[i][j] = zero;

  for (int kt = 0; kt < 64; ++kt) {
    __syncthreads();   // previous iter's ds_reads done before overwrite
    #pragma unroll
    for (int q = 0; q < 4; ++q) {
      // each instr: 64 lanes x 16B = 8 rows x 128B, LDS dest wave-uniform
      gl_lds16(wsA + aRowBase + (size_t)(q * 8 + rA) * 8192 + kt * 128 + pcA * 16,
               &As[(wid * 32 + q * 8) * 64]);
      gl_lds16(wsB + bRowBase + (size_t)(q * 8 + rA) * 8192 + kt * 128 + pcA * 16,
               &Bs[(wid * 32 + q * 8) * 64]);
    }
    __syncthreads();   // vmcnt(0) drain -> data visible

    #pragma unroll
    for (int s = 0; s < 2; ++s) {
      const int sw = ((s * 4 + quad) ^ (am & 7)) * 8;   // zero-conflict (R3/R4-verified)
      bf16x8 af[4], bfr[4];
      #pragma unroll
      for (int tm = 0; tm < 4; ++tm)
        af[tm] = *(const bf16x8*)&As[(wr * 64 + tm * 16 + am) * 64 + sw];
      #pragma unroll
      for (int tn = 0; tn < 4; ++tn)
        bfr[tn] = *(const bf16x8*)&Bs[(wc * 64 + tn * 16 + am) * 64 + sw];
      #pragma unroll
      for (int tm = 0; tm < 4; ++tm)
        #pragma unroll
        for (int tn = 0; tn < 4; ++tn)
          acc[tm][tn] = __builtin_amdgcn_mfma_f32_16x16x32_bf16(
              af[tm], bfr[tn], acc[tm][tn], 0, 0, 0);
    }
  }

  // fused LSTM epilogue: C/D col = lane&15 (c_il = 4*u + gate), row = quad*4+reg.
  const int BU   = 1024 * 2048;
  const int g    = lane & 3;
  const int base = lane & ~3;
  #pragma unroll
  for (int tn = 0; tn < 4; ++tn) {
    const int cil = wc * 64 + tn * 16 + am;
    const int col = n * 1024 + u0 + (cil >> 2);
    #pragma unroll
    for (int tm = 0; tm < 4; ++tm) {
      const int brow0 = rowbase + wr * 64 + tm * 16 + quad * 4;
      #pragma unroll
      for (int r = 0; r < 4; ++r) {
        const int brow = brow0 + r;
        const float val = acc[tm][tn][r];
        const float xs  = (g == 2) ? 2.f * val : val;       // tanh via sigmoid
        const float sg  = 1.f / (1.f + __expf(-xs));
        const float act = (g == 2) ? (2.f * sg - 1.f) : sg;
        const float ig = __shfl(act, base + 0, 64);
        const float fg = __shfl(act, base + 1, 64);
        const float gg = __shfl(act, base + 2, 64);
        const float og = __shfl(act, base + 3, 64);
        const float cold = cin[brow * 2048 + col];
        const float nc = fg * cold + ig * gg;
        const float th = 1.f - 2.f / (1.f + __expf(2.f * nc));
        const float nh = og * th;
        if (g == 0) out[brow * 2048 + col]      = nh;
        if (g == 1) out[BU + brow * 2048 + col] = nc;
      }
    }
  }
}

// ---------- fallback: round-4 fused kernel (used when ws too small) ----------
__global__ __launch_bounds__(512, 4)
void lstm_fused_fb(const float* __restrict__ x, const float* __restrict__ h,
                   const float* __restrict__ cin, const float* __restrict__ W,
                   float* __restrict__ out)
{
  __shared__ short As[128 * 64];
  __shared__ short Bs[128 * 64];
  const int tid  = threadIdx.x;
  const int lane = tid & 63;
  const int wid  = tid >> 6;
  const int wr   = wid >> 2;
  const int wq   = wid & 3;
  const int bid     = blockIdx.x;
  const int rowblk  = bid >> 6;
  const int colblk  = bid & 63;
  const int n       = colblk >> 5;
  const int u0      = (colblk & 31) * 32;
  const int rowbase = rowblk * 128;
  const int ar = tid >> 2;
  const int aq = tid & 3;
  const int bc   = tid & 127;
  const int bgt  = bc & 3;
  const int bu   = bc >> 2;
  const int kgrp = tid >> 7;
  const int gcol = bgt * 1024 + u0 + bu;
  const int am   = lane & 15;
  const int quad = lane >> 4;

  f32x4 acc[4][2];
  const f32x4 zero = {0.f, 0.f, 0.f, 0.f};
  #pragma unroll
  for (int i = 0; i < 4; ++i)
    #pragma unroll
    for (int j = 0; j < 2; ++j) acc[i][j] = zero;

  float4 areg[4];
  float  breg[16];
  auto load_tiles = [&](int kt) {
    const int blk = kt >> 4;
    const float* asrc = (blk & 1) ? h : x;
    const int cb = (blk >> 1) * 1024 + (kt & 15) * 64;
    const float4* p = (const float4*)(asrc + (rowbase + ar) * 2048 + cb + aq * 16);
    #pragma unroll
    for (int q = 0; q < 4; ++q) areg[q] = p[q];
    const int kq = kt >> 5;
    const float* wp = W + ((kq * 2 + n) * 2048 + (kt & 31) * 64 + kgrp * 16) * 4096 + gcol;
    #pragma unroll
    for (int j = 0; j < 16; ++j) breg[j] = wp[j * 4096];
  };
  load_tiles(0);
  for (int kt = 0; kt < 64; ++kt) {
    bf16x8 aw[2];
    {
      pk8 p0, p1;
      p0.u[0] = pkcvt(areg[0].x, areg[0].y); p0.u[1] = pkcvt(areg[0].z, areg[0].w);
      p0.u[2] = pkcvt(areg[1].x, areg[1].y); p0.u[3] = pkcvt(areg[1].z, areg[1].w);
      p1.u[0] = pkcvt(areg[2].x, areg[2].y); p1.u[1] = pkcvt(areg[2].z, areg[2].w);
      p1.u[2] = pkcvt(areg[3].x, areg[3].y); p1.u[3] = pkcvt(areg[3].z, areg[3].w);
      aw[0] = p0.v; aw[1] = p1.v;
    }
    bf16x8 bw[2];
    {
      pk8 q0, q1;
      #pragma unroll
      for (int j = 0; j < 4; ++j) {
        q0.u[j] = pkcvt(breg[2 * j],     breg[2 * j + 1]);
        q1.u[j] = pkcvt(breg[8 + 2 * j], breg[8 + 2 * j + 1]);
      }
      bw[0] = q0.v; bw[1] = q1.v;
    }
    __syncthreads();
    #pragma unroll
    for (int hh = 0; hh < 2; ++hh)
      *(bf16x8*)&As[ar * 64 + (((aq * 2 + hh) ^ (ar & 7)) * 8)] = aw[hh];
    #pragma unroll
    for (int hh = 0; hh < 2; ++hh)
      *(bf16x8*)&Bs[bc * 64 + (((kgrp * 2 + hh) ^ (bc & 7)) * 8)] = bw[hh];
    __syncthreads();
    if (kt < 63) load_tiles(kt + 1);
    #pragma unroll
    for (int s = 0; s < 2; ++s) {
      const int sw = ((s * 4 + quad) ^ (am & 7)) * 8;
      bf16x8 af[4], bfr[2];
      #pragma unroll
      for (int tm = 0; tm < 4; ++tm)
        af[tm] = *(const bf16x8*)&As[(wr * 64 + tm * 16 + am) * 64 + sw];
      #pragma unroll
      for (int tn = 0; tn < 2; ++tn)
        bfr[tn] = *(const bf16x8*)&Bs[(wq * 32 + tn * 16 + am) * 64 + sw];
      #pragma unroll
      for (int tm = 0; tm < 4; ++tm)
        #pragma unroll
        for (int tn = 0; tn < 2; ++tn)
          acc[tm][tn] = __builtin_amdgcn_mfma_f32_16x16x32_bf16(
              af[tm], bfr[tn], acc[tm][tn], 0, 0, 0);
    }
  }
  const int BU   = 1024 * 2048;
  const int g    = lane & 3;
  const int base = lane & ~3;
  #pragma unroll
  for (int tn = 0; tn < 2; ++tn) {
    const int cil = wq * 32 + tn * 16 + am;
    const int col = n * 1024 + u0 + (cil >> 2);
    #pragma unroll
    for (int tm = 0; tm < 4; ++tm) {
      const int brow0 = rowbase + wr * 64 + tm * 16 + quad * 4;
      #pragma unroll
      for (int r = 0; r < 4; ++r) {
        const int brow = brow0 + r;
        const float val = acc[tm][tn][r];
        const float xs  = (g == 2) ? 2.f * val : val;
        const float sg  = 1.f / (1.f + __expf(-xs));
        const float act = (g == 2) ? (2.f * sg - 1.f) : sg;
        const float ig = __shfl(act, base + 0, 64);
        const float fg = __shfl(act, base + 1, 64);
        const float gg = __shfl(act, base + 2, 64);
        const float og = __shfl(act, base + 3, 64);
        const float cold = cin[brow * 2048 + col];
        const float nc = fg * cold + ig * gg;
        const float th = 1.f - 2.f / (1.f + __expf(2.f * nc));
        const float nh = og * th;
        if (g == 0) out[brow * 2048 + col]      = nh;
        if (g == 1) out[BU + brow * 2048 + col] = nc;
      }
    }
  }
}

extern "C" void kernel_launch(void* const* d_in, const int* in_sizes, int n_in,
                              void* d_out, int out_size, void* d_ws, size_t ws_size,
                              hipStream_t stream) {
  const float* x = (const float*)d_in[0];
  const float* h = (const float*)d_in[1];
  const float* c = (const float*)d_in[2];
  const float* W = (const float*)d_in[3];
  float* out = (float*)d_out;

  const size_t WSA_BYTES = (size_t)1024 * 4096 * 2;        //  8 MB bf16 xh
  const size_t WSB_BYTES = (size_t)2 * 4096 * 4096 * 2;    // 67 MB bf16 W^T
  if (ws_size >= WSA_BYTES + WSB_BYTES) {
    char* wsA = (char*)d_ws;
    char* wsB = (char*)d_ws + WSA_BYTES;
    prep_xh<<<dim3(2048), dim3(256), 0, stream>>>(x, h, wsA);
    prep_w<<<dim3(8192), dim3(256), 0, stream>>>(W, wsB);
    lstm_mm<<<dim3(512), dim3(256), 0, stream>>>(wsA, wsB, c, out);
  } else {
    lstm_fused_fb<<<dim3(512), dim3(512), 0, stream>>>(x, h, c, W, out);
  }
}